// Round 14
// baseline (410.863 us; speedup 1.0000x reference)
//
#include <hip/hip_runtime.h>
#include <math.h>

#define NS 4096
#define NF 512
#define NB 16
#define NC 10
#define HSIZE 8192
#define HMASK 8191
#define HEMPTY 0xFFFFFFFFu
#define TSR 128                      // stripe tile rows
#define TSC 16                       // stripe cols
#define NSEG 4                       // segments along S
#define SEGR (NS / NSEG)             // 1024 rows per segment
#define WS_P_OFF  1024
#define P2_BYTES (NB * NF * NSEG * 16 * 4)            // 2 MB
#define WS_XT_OFF (WS_P_OFF + P2_BYTES)               // counts | P2 | XT

// ---------------- helpers ----------------
__device__ __forceinline__ float wave_reduce_add(float v) {
    #pragma unroll
    for (int off = 32; off > 0; off >>= 1) v += __shfl_down(v, off, 64);
    return v;
}

__device__ __forceinline__ unsigned int pat_of(float x) {
    if (x != x) x = 0.f;                       // nan_to_num for the hash
    unsigned int p = __float_as_uint(x);
    return (p == 0x80000000u) ? 0u : p;        // -0.0 == +0.0 value semantics
}

// ---------------- kernel S: segmented stripe transpose + moment stats --------------
// R14 change (schedule-only): barrier FIRST, then issue next-tile loads, then
// compute. Previously loads were issued before __syncthreads(), whose implicit
// vmcnt(0) drain force-completed them AT the barrier (load latency exposed once
// per tile). Now the load wait sits at the stage-write after compute -> hidden.
__launch_bounds__(512, 4)
__global__ void stripe_stats_kernel(const float* __restrict__ X,
                                    float* __restrict__ XT,
                                    const int* __restrict__ y,
                                    float* __restrict__ P2,
                                    int* __restrict__ counts_i) {
    __shared__ float t[2][TSR][TSC + 1];       // 2 x 8.7 KB, bank-safe pad 17
    __shared__ int ys[2][TSR];
    __shared__ int hist[NC];
    const int b   = blockIdx.x;
    const int f0  = blockIdx.y * TSC;
    const int seg = blockIdx.z;
    const int tid = threadIdx.x;
    const bool do_hist = (blockIdx.y == 0);
    if (do_hist && tid < NC) hist[tid] = 0;    // ordered before use by first barrier

    const int lrow = tid >> 2, lq = tid & 3;   // load mapping: 128 rows x 4 quads
    const int col  = tid >> 5, rq = tid & 31;  // stats mapping: 16 cols x 32 lanes

    const int sbase = seg * SEGR;
    const float* Xb = X + (size_t)b * NS * NF + f0 + lq * 4;
    const int*   yb = y + (size_t)b * NS;
    float* XTc = XT + ((size_t)b * NF + f0 + col) * NS;   // this thread's column

    float sum = 0.f, sumsq = 0.f, sumabs = 0.f, maxabs = 0.f, nancnt = 0.f;
    float csum[NC];
    #pragma unroll
    for (int c = 0; c < NC; c++) csum[c] = 0.f;

    // prologue: load tile 0 and stage into buf 0 (published by first loop barrier)
    {
        const float4 xc = *(const float4*)(Xb + (size_t)(sbase + lrow) * NF);
        t[0][lrow][lq * 4 + 0] = xc.x; t[0][lrow][lq * 4 + 1] = xc.y;
        t[0][lrow][lq * 4 + 2] = xc.z; t[0][lrow][lq * 4 + 3] = xc.w;
        if (tid < TSR / 4) {
            const int4 y4 = *(const int4*)(yb + sbase + tid * 4);
            ys[0][tid * 4 + 0] = y4.x; ys[0][tid * 4 + 1] = y4.y;
            ys[0][tid * 4 + 2] = y4.z; ys[0][tid * 4 + 3] = y4.w;
        }
    }

    for (int it = 0; it < SEGR / TSR; ++it) {  // 8 tiles per segment
        const int cur = it & 1;
        const int s0 = sbase + it * TSR;
        const bool more = (it + 1 < SEGR / TSR);

        __syncthreads();                       // publishes buf[cur]

        float4 xn = make_float4(0.f, 0.f, 0.f, 0.f);
        int4 yn4 = make_int4(0, 0, 0, 0);
        if (more) {                            // loads IN FLIGHT during compute
            xn = *(const float4*)(Xb + (size_t)(s0 + TSR + lrow) * NF);
            if (tid < TSR / 4) yn4 = *(const int4*)(yb + s0 + TSR + tid * 4);
        }

        if (do_hist && tid < TSR) atomicAdd(&hist[ys[cur][tid]], 1);

        #pragma unroll
        for (int j = 0; j < 4; j++) {          // rows rq+32j: conflict-free banks
            const int r = rq + 32 * j;
            const float raw = t[cur][r][col];  // ONE read feeds XT + stats
            const int yc = ys[cur][r];
            XTc[s0 + r] = raw;                 // 128B/wave contiguous per j
            float x = raw;
            if (x != x) { nancnt += 1.f; x = 0.f; }          // nan_to_num
            sum += x;
            sumsq = fmaf(x, x, sumsq);
            const float a = fabsf(x);
            sumabs += a;
            maxabs = fmaxf(maxabs, a);
            #pragma unroll
            for (int c = 0; c < NC; c++) csum[c] += (yc == c) ? x : 0.f;
        }
        if (more) {                            // stage NEXT tile (waits loads HERE,
            const int nb = cur ^ 1;            // after compute -> latency hidden)
            t[nb][lrow][lq * 4 + 0] = xn.x; t[nb][lrow][lq * 4 + 1] = xn.y;
            t[nb][lrow][lq * 4 + 2] = xn.z; t[nb][lrow][lq * 4 + 3] = xn.w;
            if (tid < TSR / 4) {
                ys[nb][tid * 4 + 0] = yn4.x; ys[nb][tid * 4 + 1] = yn4.y;
                ys[nb][tid * 4 + 2] = yn4.z; ys[nb][tid * 4 + 3] = yn4.w;
            }
        }
    }

    // per-segment partials: width-32 shfl reduce, lane rq==0 stores 15 stats
    float st[15] = { sum, sumsq, sumabs, nancnt, maxabs,
                     csum[0], csum[1], csum[2], csum[3], csum[4],
                     csum[5], csum[6], csum[7], csum[8], csum[9] };
    #pragma unroll
    for (int s = 0; s < 15; s++) {
        float v = st[s];
        #pragma unroll
        for (int off = 16; off > 0; off >>= 1) {
            const float o = __shfl_down(v, off, 32);
            v = (s == 4) ? fmaxf(v, o) : v + o;
        }
        if (rq == 0)
            P2[(((size_t)b * NF + f0 + col) * NSEG + seg) * 16 + s] = v;
    }
    if (do_hist) {
        __syncthreads();                       // all hist atomics done
        if (tid < NC) atomicAdd(&counts_i[b * NC + tid], hist[tid]);
    }
}

// ---------------- kernel 2: SNAPSHOT write/read hash-unique + finalize + MLP ------
// R14 protocol (2 barriers/round, no tags, no atomics):
//   W: elements whose last post-barrier snapshot of their slot was EMPTY write pat.
//   barrier
//   R: all unsettled read their slot (uniform post-barrier snapshot):
//      ==pat -> settled; ==EMPTY -> will write next W; else -> advance (dbl hash).
//   __syncthreads_count(uns) -> uniform exit + R->W ordering barrier.
// Invariants: classification only on post-barrier snapshots => same-value elements
// evolve in lockstep; a slot is written only while EMPTY and never after (a writer's
// EMPTY-knowledge comes from the same snapshot that would have settled it otherwise)
// => final table holds EXACTLY ONE slot per distinct value => uniq = occupied count.
__launch_bounds__(512, 8)
__global__ void fused_hash_mlp(const float* __restrict__ XT,
                               const float* __restrict__ P2,
                               const int* __restrict__ counts_i,
                               const float* __restrict__ w1,
                               const float* __restrict__ b1,
                               const float* __restrict__ w2,
                               const float* __restrict__ b2,
                               float* __restrict__ out) {
    __shared__ __align__(16) unsigned int T[HSIZE];   // 32 KB, multi-purpose

    const int w = blockIdx.x;
    const int g = (w & 7) * 1024 + (w >> 3);   // XCD swizzle, bijection over [0,8192)
    const int b = g >> 9;
    const int f = g & (NF - 1);
    const int tid = threadIdx.x;
    const int wave = tid >> 6, lane = tid & 63;

    // prefetch BEFORE init: loads in flight while the table is cleared
    const float4* Xc4 = (const float4*)(XT + ((size_t)b * NF + f) * NS);
    const float4 xa = Xc4[tid];
    const float4 xb = Xc4[512 + tid];

    uint4* h4 = (uint4*)T;
    const uint4 e4 = make_uint4(HEMPTY, HEMPTY, HEMPTY, HEMPTY);
    #pragma unroll
    for (int i = 0; i < HSIZE / 4 / 512; i++) h4[i * 512 + tid] = e4;
    __syncthreads();                           // table cleared before round 1 writes

    unsigned int pat[8] = { pat_of(xa.x), pat_of(xa.y), pat_of(xa.z), pat_of(xa.w),
                            pat_of(xb.x), pat_of(xb.y), pat_of(xb.z), pat_of(xb.w) };
    unsigned int slot[8], step[8];
    #pragma unroll
    for (int e = 0; e < 8; e++) {
        slot[e] = (pat[e] * 2654435761u) >> 19;          // top 13 bits -> [0,8192)
        step[e] = (pat[e] & 0x1FFFu) | 1u;               // odd -> full cycle mod 8192
    }

    int uns = 0xFF;        // unsettled elements
    int wr  = 0xFF;        // elements whose slot snapshot was EMPTY (table starts empty)
    for (;;) {
        #pragma unroll
        for (int e = 0; e < 8; e++)            // W: batched writes, no returns
            if (wr & (1 << e)) T[slot[e]] = pat[e];
        __syncthreads();
        int newwr = 0;
        #pragma unroll
        for (int e = 0; e < 8; e++) {          // R: uniform post-barrier snapshot
            if (uns & (1 << e)) {
                const unsigned int v = T[slot[e]];
                if (v == pat[e])       uns &= ~(1 << e);              // value placed
                else if (v == HEMPTY)  newwr |= (1 << e);             // write next W
                else                   slot[e] = (slot[e] + step[e]) & HMASK; // probe
            }
        }
        wr = newwr;
        if (__syncthreads_count(uns) == 0) break;   // exit + R->W ordering
    }

    // uniq = occupied slots (exactly one per distinct value)
    float uniq = 0.f;
    #pragma unroll
    for (int i = 0; i < 4; i++) {
        const uint4 v = h4[i * 512 + tid];
        uniq += (v.x != HEMPTY) + (v.y != HEMPTY) + (v.z != HEMPTY) + (v.w != HEMPTY);
    }
    __syncthreads();                           // scan reads done before re-alias

    // -------- reduce uniq + finalize + MLP (T region re-aliased) -----------------
    float* r = (float*)T;                      // [0,8): wave uniq partials
    float* stats_s = r + 32;                   // [32,38)
    float* h_s = r + 64;                       // [64,128)

    uniq = wave_reduce_add(uniq);
    if (lane == 0) r[wave] = uniq;
    __syncthreads();

    if (tid == 0) {
        float u = 0.f;
        #pragma unroll
        for (int i = 0; i < 8; i++) u += r[i];
        const float* Pp = P2 + ((size_t)b * NF + f) * (NSEG * 16);
        float S[15];
        #pragma unroll
        for (int s = 0; s < 15; s++) {
            float v0 = Pp[s], v1 = Pp[16 + s], v2 = Pp[32 + s], v3 = Pp[48 + s];
            S[s] = (s == 4) ? fmaxf(fmaxf(v0, v1), fmaxf(v2, v3))
                            : (v0 + v1) + (v2 + v3);
        }
        const float invS = 1.f / (float)NS;
        const float gmean    = S[0] * invS;
        const float variance = fmaxf(S[1] * invS - gmean * gmean, 0.f);  // biased
        const float mean_abs = S[2] * invS;
        const float missing  = S[3] * invS;
        const float max_abs  = S[4];
        float between = 0.f;
        #pragma unroll
        for (int c = 0; c < NC; c++) {
            const float cnt = (float)counts_i[b * NC + c];
            const float cm  = S[5 + c] / fmaxf(cnt, 1.f);
            const float d   = cm - gmean;
            between = fmaf(cnt * d, d, between);
        }
        between *= invS;                                   // counts.sum() == NS
        const float target = between / fmaxf(variance, 1e-6f);
        float st6[6] = { target, missing, u * invS, variance, mean_abs, max_abs };
        #pragma unroll
        for (int i = 0; i < 6; i++) {
            float v = st6[i];
            if (!(fabsf(v) < INFINITY)) v = 0.f;           // nan_to_num
            stats_s[i] = v;
        }
    }
    __syncthreads();

    // MLP epilogue: 6 -> 64 (exact GELU) -> 128
    if (tid < 64) {
        float z = b1[tid];
        #pragma unroll
        for (int i = 0; i < 6; i++) z = fmaf(stats_s[i], w1[i * 64 + tid], z);
        h_s[tid] = 0.5f * z * (1.f + erff(z * 0.70710678118654752440f));
    }
    __syncthreads();
    if (tid < 128) {
        float o = b2[tid];
        #pragma unroll
        for (int j = 0; j < 64; j++) o = fmaf(h_s[j], w2[j * 128 + tid], o);
        out[(size_t)g * 128 + tid] = o;
    }
}

// ---------------- fallback path (round-0 proven, strided) ----------------
__global__ void count_classes_kernel(const int* __restrict__ y, float* __restrict__ counts) {
    __shared__ int hist[NC];
    const int b = blockIdx.x;
    if (threadIdx.x < NC) hist[threadIdx.x] = 0;
    __syncthreads();
    for (int s = threadIdx.x; s < NS; s += blockDim.x)
        atomicAdd(&hist[y[b * NS + s]], 1);
    __syncthreads();
    if (threadIdx.x < NC) counts[b * NC + threadIdx.x] = (float)hist[threadIdx.x];
}

__device__ __forceinline__ float wave_reduce_max64(float v) {
    #pragma unroll
    for (int off = 32; off > 0; off >>= 1) v = fmaxf(v, __shfl_down(v, off, 64));
    return v;
}

__launch_bounds__(256)
__global__ void fused_stats_mlp_kernel(const float* __restrict__ X,
                                       const int* __restrict__ y,
                                       const float* __restrict__ counts,
                                       const float* __restrict__ w1,
                                       const float* __restrict__ b1,
                                       const float* __restrict__ w2,
                                       const float* __restrict__ b2,
                                       float* __restrict__ out) {
    __shared__ unsigned int hash[HSIZE];
    __shared__ float red[4][16];
    __shared__ float stats_s[6];
    __shared__ float h_s[64];

    const int w = blockIdx.x;
    const int g = (w & 7) * 1024 + (w >> 3);
    const int b = g >> 9;
    const int f = g & (NF - 1);
    const int tid = threadIdx.x;

    #pragma unroll
    for (int i = 0; i < HSIZE / 256; i++) hash[tid + i * 256] = HEMPTY;
    __syncthreads();

    const float* Xp = X + (size_t)b * NS * NF + f;
    const int*   yp = y + b * NS;

    float sum = 0.f, sumsq = 0.f, sumabs = 0.f, maxabs = 0.f, nancnt = 0.f, uniq = 0.f;
    float csum[NC];
    #pragma unroll
    for (int c = 0; c < NC; c++) csum[c] = 0.f;

    #pragma unroll
    for (int k0 = 0; k0 < 16; k0 += 8) {
        float xv[8]; int yv[8];
        #pragma unroll
        for (int k = 0; k < 8; k++) {
            const int s = (k0 + k) * 256 + tid;
            xv[k] = Xp[(size_t)s * NF];
            yv[k] = yp[s];
        }
        #pragma unroll
        for (int k = 0; k < 8; k++) {
            float x = xv[k];
            if (x != x) { nancnt += 1.f; x = 0.f; }
            sum += x;
            sumsq = fmaf(x, x, sumsq);
            const float a = fabsf(x);
            sumabs += a;
            maxabs = fmaxf(maxabs, a);
            const int yc = yv[k];
            #pragma unroll
            for (int c = 0; c < NC; c++) csum[c] += (yc == c) ? x : 0.f;
            unsigned int pat = __float_as_uint(x);
            if (pat == 0x80000000u) pat = 0u;
            unsigned int slot = (pat * 2654435761u) >> 19;
            for (;;) {
                const unsigned int old = atomicCAS(&hash[slot], HEMPTY, pat);
                if (old == HEMPTY) { uniq += 1.f; break; }
                if (old == pat) break;
                slot = (slot + 1) & HMASK;
            }
        }
    }

    sum    = wave_reduce_add(sum);
    sumsq  = wave_reduce_add(sumsq);
    sumabs = wave_reduce_add(sumabs);
    nancnt = wave_reduce_add(nancnt);
    uniq   = wave_reduce_add(uniq);
    maxabs = wave_reduce_max64(maxabs);
    #pragma unroll
    for (int c = 0; c < NC; c++) csum[c] = wave_reduce_add(csum[c]);

    const int wave = tid >> 6, lane = tid & 63;
    if (lane == 0) {
        red[wave][0] = sum;    red[wave][1] = sumsq; red[wave][2] = sumabs;
        red[wave][3] = nancnt; red[wave][4] = uniq;  red[wave][5] = maxabs;
        #pragma unroll
        for (int c = 0; c < NC; c++) red[wave][6 + c] = csum[c];
    }
    __syncthreads();

    if (tid == 0) {
        float t[16];
        #pragma unroll
        for (int v = 0; v < 16; v++) t[v] = red[0][v];
        #pragma unroll
        for (int wv = 1; wv < 4; wv++) {
            #pragma unroll
            for (int v = 0; v < 16; v++) {
                if (v == 5) t[v] = fmaxf(t[v], red[wv][v]);
                else        t[v] += red[wv][v];
            }
        }
        const float invS = 1.f / (float)NS;
        const float gmean    = t[0] * invS;
        const float variance = fmaxf(t[1] * invS - gmean * gmean, 0.f);
        const float mean_abs = t[2] * invS;
        const float missing  = t[3] * invS;
        const float n_unique = t[4];
        const float max_abs  = t[5];
        float between = 0.f;
        #pragma unroll
        for (int c = 0; c < NC; c++) {
            const float cnt = counts[b * NC + c];
            const float cm  = t[6 + c] / fmaxf(cnt, 1.f);
            const float d   = cm - gmean;
            between += cnt * d * d;
        }
        between *= invS;
        const float target = between / fmaxf(variance, 1e-6f);
        float st[6] = { target, missing, n_unique * invS, variance, mean_abs, max_abs };
        #pragma unroll
        for (int i = 0; i < 6; i++) {
            float v = st[i];
            if (!(fabsf(v) < INFINITY)) v = 0.f;
            stats_s[i] = v;
        }
    }
    __syncthreads();

    if (tid < 64) {
        float z = b1[tid];
        #pragma unroll
        for (int i = 0; i < 6; i++) z = fmaf(stats_s[i], w1[i * 64 + tid], z);
        h_s[tid] = 0.5f * z * (1.f + erff(z * 0.70710678118654752440f));
    }
    __syncthreads();
    if (tid < 128) {
        float o = b2[tid];
        #pragma unroll
        for (int j = 0; j < 64; j++) o = fmaf(h_s[j], w2[j * 128 + tid], o);
        out[(size_t)g * 128 + tid] = o;
    }
}

extern "C" void kernel_launch(void* const* d_in, const int* in_sizes, int n_in,
                              void* d_out, int out_size, void* d_ws, size_t ws_size,
                              hipStream_t stream) {
    const float* X  = (const float*)d_in[0];
    const int*   y  = (const int*)d_in[1];
    const float* w1 = (const float*)d_in[2];
    const float* b1 = (const float*)d_in[3];
    const float* w2 = (const float*)d_in[4];
    const float* b2 = (const float*)d_in[5];
    float* out = (float*)d_out;

    const size_t xt_bytes = (size_t)NB * NF * NS * sizeof(float);   // 128 MB
    if (ws_size >= (size_t)WS_XT_OFF + xt_bytes) {
        int*   counts_i = (int*)d_ws;                       // NB*NC ints
        float* P2 = (float*)((char*)d_ws + WS_P_OFF);       // [B][F][NSEG][16]
        float* XT = (float*)((char*)d_ws + WS_XT_OFF);
        hipMemsetAsync(d_ws, 0, NB * NC * sizeof(int), stream);
        stripe_stats_kernel<<<dim3(NB, NF / TSC, NSEG), 512, 0, stream>>>(
            X, XT, y, P2, counts_i);
        fused_hash_mlp<<<NB * NF, 512, 0, stream>>>(
            XT, P2, counts_i, w1, b1, w2, b2, out);
    } else {
        // workspace too small: proven strided path (round-0 structure)
        float* counts = (float*)d_ws;
        count_classes_kernel<<<NB, 256, 0, stream>>>(y, counts);
        fused_stats_mlp_kernel<<<NB * NF, 256, 0, stream>>>(X, y, counts, w1, b1, w2, b2, out);
    }
}